// Round 1
// baseline (3194.404 us; speedup 1.0000x reference)
//
#include <hip/hip_runtime.h>
#include <hip/hip_bf16.h>

// Problem constants
#define Bz 64
#define Nz 512
#define Ez 1024
#define Hz 16
#define DHz 64

static constexpr int MROWS = Bz * Nz;   // 32768
static constexpr int NQKV  = 3 * Ez;    // 3072

typedef __attribute__((ext_vector_type(8))) short bf16x8_t;  // 8 bf16 = 4 VGPRs
typedef __attribute__((ext_vector_type(4))) float f32x4_t;

__device__ __forceinline__ unsigned short f2bf(float f) {
    union { float f; unsigned u; } v; v.f = f;
    unsigned r = v.u + 0x7FFFu + ((v.u >> 16) & 1u);   // round-to-nearest-even
    return (unsigned short)(r >> 16);
}
__device__ __forceinline__ float bf2f(unsigned short h) {
    union { unsigned u; float f; } v; v.u = ((unsigned)h) << 16;
    return v.f;
}

// ---------------------------------------------------------------------------
// Convert fp32 -> bf16 (packed, vectorized)
__global__ void cvt_f32_bf16(const float* __restrict__ in,
                             unsigned short* __restrict__ out, int n4) {
    int id = blockIdx.x * blockDim.x + threadIdx.x;
    int stride = gridDim.x * blockDim.x;
    for (int i = id; i < n4; i += stride) {
        float4 f = ((const float4*)in)[i];
        ushort4 o;
        o.x = f2bf(f.x); o.y = f2bf(f.y); o.z = f2bf(f.z); o.w = f2bf(f.w);
        ((ushort4*)out)[i] = o;
    }
}

// Convert + transpose: in [K][Ncols] fp32 row-major -> out [Ncols][K] bf16
__global__ void cvt_transpose(const float* __restrict__ in,
                              unsigned short* __restrict__ out,
                              int K, int Ncols) {
    int k = blockIdx.y;
    int n = blockIdx.x * blockDim.x + threadIdx.x;
    out[(long)n * K + k] = f2bf(in[(long)k * Ncols + n]);
}

// ---------------------------------------------------------------------------
// bf16 MFMA GEMM: C[M][Ncols] = A[M][K] @ BT[Ncols][K]^T + bias
// 128x128 block tile, BK=32, 256 threads (4 waves, 2x2 of 64x64 per wave)
template<bool OUT_BF16>
__global__ __launch_bounds__(256)
void gemm_mfma(const unsigned short* __restrict__ A,
               const unsigned short* __restrict__ BT,
               const float* __restrict__ bias,
               void* __restrict__ C,
               int M, int Ncols, int K) {
    const int tid  = threadIdx.x;
    const int wave = tid >> 6;
    const int lane = tid & 63;
    const int wm = (wave >> 1) * 64;
    const int wn = (wave & 1) * 64;
    const int l16 = lane & 15;
    const int lq  = lane >> 4;

    const int rowBase = blockIdx.y * 128;
    const int colBase = blockIdx.x * 128;

    __shared__ __align__(16) unsigned short As[128][32];
    __shared__ __align__(16) unsigned short Bs[128][32];

    f32x4_t acc[4][4];
#pragma unroll
    for (int i = 0; i < 4; i++)
#pragma unroll
        for (int j = 0; j < 4; j++) {
            f32x4_t z = {0.0f, 0.0f, 0.0f, 0.0f};
            acc[i][j] = z;
        }

    for (int k0 = 0; k0 < K; k0 += 32) {
        __syncthreads();
#pragma unroll
        for (int cc = 0; cc < 2; cc++) {
            int c = tid + cc * 256;           // 512 chunks of 16B per tile
            int r = c >> 2, q = c & 3;
            *(bf16x8_t*)&As[r][q * 8] =
                *(const bf16x8_t*)&A[(long)(rowBase + r) * K + k0 + q * 8];
            *(bf16x8_t*)&Bs[r][q * 8] =
                *(const bf16x8_t*)&BT[(long)(colBase + r) * K + k0 + q * 8];
        }
        __syncthreads();

        bf16x8_t af[4], bfr[4];
#pragma unroll
        for (int i = 0; i < 4; i++)
            af[i] = *(bf16x8_t*)&As[wm + i * 16 + l16][lq * 8];
#pragma unroll
        for (int j = 0; j < 4; j++)
            bfr[j] = *(bf16x8_t*)&Bs[wn + j * 16 + l16][lq * 8];
#pragma unroll
        for (int i = 0; i < 4; i++)
#pragma unroll
            for (int j = 0; j < 4; j++)
                acc[i][j] = __builtin_amdgcn_mfma_f32_16x16x32_bf16(
                    af[i], bfr[j], acc[i][j], 0, 0, 0);
    }

#pragma unroll
    for (int i = 0; i < 4; i++) {
#pragma unroll
        for (int j = 0; j < 4; j++) {
            int col = colBase + wn + j * 16 + l16;
            float bv = bias[col];
#pragma unroll
            for (int r = 0; r < 4; r++) {
                int row = rowBase + wm + i * 16 + lq * 4 + r;
                float v = acc[i][j][r] + bv;
                if (OUT_BF16)
                    ((unsigned short*)C)[(long)row * Ncols + col] = f2bf(v);
                else
                    ((float*)C)[(long)row * Ncols + col] = v;
            }
        }
    }
}

// ---------------------------------------------------------------------------
// Attention: one block per (b,h). K,V staged in LDS (bf16, XOR-swizzled 16B
// chunks). For each 8-row q-group: scores (fp32 VALU), mask+exp, row-sum,
// PV, write y (bf16) laid out [b*N+n][h*64+dh] == [b,n,e].
__global__ __launch_bounds__(512)
void attn_kernel(const unsigned short* __restrict__ qkv,  // [32768][3072] bf16
                 const int* __restrict__ adj,             // [512][512]
                 unsigned short* __restrict__ y)          // [32768][1024] bf16
{
    const int h = blockIdx.x;
    const int b = blockIdx.y;
    const int tid  = threadIdx.x;   // 0..511
    const int lane = tid & 63;
    const int wv   = tid >> 6;      // 0..7

    __shared__ __align__(16) unsigned short Ks[512][64];
    __shared__ __align__(16) unsigned short Vs[512][64];
    __shared__ __align__(16) float ps[8][512];
    __shared__ __align__(16) float qs[8][64];
    __shared__ float partial[8][8];
    __shared__ float rinv[8];

    const long rowB = (long)b * Nz;

    // Stage K, V (8 chunk-iterations each, coalesced 128B per 8 threads)
    for (int c = tid; c < 4096; c += 512) {
        int n = c >> 3, cc = c & 7;
        int sc = cc ^ (n & 7);
        *(bf16x8_t*)&Ks[n][sc * 8] =
            *(const bf16x8_t*)&qkv[(rowB + n) * NQKV + Ez + h * DHz + cc * 8];
        *(bf16x8_t*)&Vs[n][sc * 8] =
            *(const bf16x8_t*)&qkv[(rowB + n) * NQKV + 2 * Ez + h * DHz + cc * 8];
    }
    // (barrier below covers staging visibility)

    for (int rg = 0; rg < 64; rg++) {
        const int n0 = rg * 8;
        // stage q rows (fp32)
        {
            int r = tid >> 6, d = tid & 63;
            qs[r][d] = bf2f(qkv[(rowB + n0 + r) * NQKV + h * DHz + d]);
        }
        __syncthreads();  // B1: qs (and on rg==0, K/V) visible; prev ps reads done

        // ---- scores: thread tid owns column j = tid, 8 rows
        const int j = tid;
        float accv[8];
#pragma unroll
        for (int r = 0; r < 8; r++) accv[r] = 0.0f;
#pragma unroll
        for (int dc = 0; dc < 8; dc++) {
            bf16x8_t k8 = *(bf16x8_t*)&Ks[j][(dc ^ (j & 7)) * 8];
            float kf[8];
#pragma unroll
            for (int i = 0; i < 8; i++) kf[i] = bf2f((unsigned short)k8[i]);
#pragma unroll
            for (int r = 0; r < 8; r++) {
                float4 qa = *(const float4*)&qs[r][dc * 8];
                float4 qb = *(const float4*)&qs[r][dc * 8 + 4];
                accv[r] += kf[0] * qa.x + kf[1] * qa.y + kf[2] * qa.z + kf[3] * qa.w
                         + kf[4] * qb.x + kf[5] * qb.y + kf[6] * qb.z + kf[7] * qb.w;
            }
        }
        // ---- mask + exp (softmax w/o max-sub: scores bounded, exp safe)
#pragma unroll
        for (int r = 0; r < 8; r++) {
            int qrow = n0 + r;
            bool m = (adj[(long)qrow * Nz + j] != 0) || (j == qrow);
            float e = m ? __expf(accv[r] * 0.125f) : 0.0f;
            ps[r][j] = e;
            accv[r] = e;
        }
        // ---- row sums: wave butterfly + cross-wave
#pragma unroll
        for (int r = 0; r < 8; r++) {
            float v = accv[r];
            for (int off = 32; off; off >>= 1) v += __shfl_xor(v, off, 64);
            if (lane == 0) partial[r][wv] = v;
        }
        __syncthreads();  // B2
        if (tid < 8) {
            float s = 0.0f;
#pragma unroll
            for (int w = 0; w < 8; w++) s += partial[tid][w];
            rinv[tid] = 1.0f / s;
        }
        __syncthreads();  // B3: ps + rinv ready

        // ---- PV: wave wv covers j in [wv*64, wv*64+64), lane owns d=lane
        float yacc[8];
#pragma unroll
        for (int r = 0; r < 8; r++) yacc[r] = 0.0f;
        const int j0 = wv * 64;
        const int d  = lane;
        for (int jj = 0; jj < 64; jj += 4) {
            float vv[4];
#pragma unroll
            for (int u = 0; u < 4; u++) {
                int jc = j0 + jj + u;
                vv[u] = bf2f(Vs[jc][((d >> 3) ^ (jc & 7)) * 8 + (d & 7)]);
            }
#pragma unroll
            for (int r = 0; r < 8; r++) {
                float4 p4 = *(const float4*)&ps[r][j0 + jj];
                yacc[r] += p4.x * vv[0] + p4.y * vv[1] + p4.z * vv[2] + p4.w * vv[3];
            }
        }
        __syncthreads();  // B4: all ps reads done -> reuse ps as reduction buf

        float* red = &ps[0][0];  // [8 waves][8 rows][64 d]
#pragma unroll
        for (int r = 0; r < 8; r++) red[(wv * 8 + r) * 64 + d] = yacc[r];
        __syncthreads();  // B5

        {
            int r = wv;  // each wave reduces one row, lane = d
            float s = 0.0f;
#pragma unroll
            for (int w = 0; w < 8; w++) s += red[(w * 8 + r) * 64 + lane];
            s *= rinv[r];
            y[(rowB + n0 + r) * Ez + h * DHz + lane] = f2bf(s);
        }
        // next iteration's B1 separates red reads from next ps writes
    }
}

// ---------------------------------------------------------------------------
extern "C" void kernel_launch(void* const* d_in, const int* in_sizes, int n_in,
                              void* d_out, int out_size, void* d_ws, size_t ws_size,
                              hipStream_t stream) {
    const float* x     = (const float*)d_in[0];
    const float* Wqkv  = (const float*)d_in[1];
    const float* bqkv  = (const float*)d_in[2];
    const float* Wproj = (const float*)d_in[3];
    const float* bproj = (const float*)d_in[4];
    const int*   adj   = (const int*)d_in[5];
    float* out = (float*)d_out;

    char* ws = (char*)d_ws;
    unsigned short* xb     = (unsigned short*)(ws);                 //  67 MB
    unsigned short* qkv    = (unsigned short*)(ws + 67108864);      // 201 MB
    unsigned short* yb     = (unsigned short*)(ws + 268435456);     //  67 MB
    unsigned short* WqkvT  = (unsigned short*)(ws + 335544320);     //   6 MB
    unsigned short* WprojT = (unsigned short*)(ws + 341835776);     //   2 MB

    // 1. casts / transposes
    cvt_f32_bf16<<<8192, 256, 0, stream>>>(x, xb, (Bz * Nz * Ez) / 4);
    cvt_transpose<<<dim3(NQKV / 256, Ez), 256, 0, stream>>>(Wqkv, WqkvT, Ez, NQKV);
    cvt_transpose<<<dim3(Ez / 256, Ez), 256, 0, stream>>>(Wproj, WprojT, Ez, Ez);

    // 2. QKV projection: qkv = xb @ Wqkv + bqkv   (bf16 out)
    gemm_mfma<true><<<dim3(NQKV / 128, MROWS / 128), 256, 0, stream>>>(
        xb, WqkvT, bqkv, qkv, MROWS, NQKV, Ez);

    // 3. masked attention per (b,h)
    attn_kernel<<<dim3(Hz, Bz), 512, 0, stream>>>(qkv, adj, yb);

    // 4. output projection: out = yb @ Wproj + bproj  (fp32 out)
    gemm_mfma<false><<<dim3(Ez / 128, MROWS / 128), 256, 0, stream>>>(
        yb, WprojT, bproj, out, MROWS, Ez, Ez);
}

// Round 2
// 802.918 us; speedup vs baseline: 3.9785x; 3.9785x over previous
//
#include <hip/hip_runtime.h>
#include <hip/hip_bf16.h>

// Problem constants
#define Bz 64
#define Nz 512
#define Ez 1024
#define Hz 16
#define DHz 64

static constexpr int MROWS = Bz * Nz;   // 32768
static constexpr int NQKV  = 3 * Ez;    // 3072

typedef __attribute__((ext_vector_type(8))) short bf16x8_t;  // 8 bf16 = 4 VGPRs
typedef __attribute__((ext_vector_type(4))) float f32x4_t;
typedef __attribute__((ext_vector_type(4))) unsigned u32x4_t;

union FragU { bf16x8_t h; u32x4_t u; };

__device__ __forceinline__ unsigned short f2bf(float f) {
    union { float f; unsigned u; } v; v.f = f;
    unsigned r = v.u + 0x7FFFu + ((v.u >> 16) & 1u);   // round-to-nearest-even
    return (unsigned short)(r >> 16);
}
__device__ __forceinline__ float bf2f(unsigned short h) {
    union { unsigned u; float f; } v; v.u = ((unsigned)h) << 16;
    return v.f;
}
// pack two non-negative floats to bf16 pair (lo | hi<<16), round-half-up
__device__ __forceinline__ unsigned packbf(float a, float b) {
    union { float f; unsigned u; } x, y; x.f = a; y.f = b;
    return ((x.u + 0x8000u) >> 16) | ((y.u + 0x8000u) & 0xFFFF0000u);
}

// async global->LDS, 16B per lane. LDS dest = wave-uniform base + lane*16.
__device__ __forceinline__ void async16(const unsigned short* g, unsigned short* l) {
    __builtin_amdgcn_global_load_lds(
        (const __attribute__((address_space(1))) void*)g,
        (__attribute__((address_space(3))) void*)l, 16, 0, 0);
}

// ---------------------------------------------------------------------------
// Convert fp32 -> bf16 (packed, vectorized)
__global__ void cvt_f32_bf16(const float* __restrict__ in,
                             unsigned short* __restrict__ out, int n4) {
    int id = blockIdx.x * blockDim.x + threadIdx.x;
    int stride = gridDim.x * blockDim.x;
    for (int i = id; i < n4; i += stride) {
        float4 f = ((const float4*)in)[i];
        ushort4 o;
        o.x = f2bf(f.x); o.y = f2bf(f.y); o.z = f2bf(f.z); o.w = f2bf(f.w);
        ((ushort4*)out)[i] = o;
    }
}

// Convert + transpose: in [K][Ncols] fp32 row-major -> out [Ncols][K] bf16
__global__ void cvt_transpose(const float* __restrict__ in,
                              unsigned short* __restrict__ out,
                              int K, int Ncols) {
    int k = blockIdx.y;
    int n = blockIdx.x * blockDim.x + threadIdx.x;
    out[(long)n * K + k] = f2bf(in[(long)k * Ncols + n]);
}

// adj[512][512] int -> bitmask adjm[512][8] u64, self-loops baked in
__global__ void build_adjm(const int* __restrict__ adj,
                           unsigned long long* __restrict__ adjm) {
    int id = blockIdx.x * blockDim.x + threadIdx.x;   // 0..4095
    int n = id >> 3, w = id & 7;
    const int4* r4 = (const int4*)(adj + (long)n * Nz + w * 64);
    unsigned long long m = 0;
#pragma unroll
    for (int c = 0; c < 16; c++) {
        int4 v = r4[c];
        unsigned long long bits =
            (unsigned long long)(v.x != 0) | ((unsigned long long)(v.y != 0) << 1) |
            ((unsigned long long)(v.z != 0) << 2) | ((unsigned long long)(v.w != 0) << 3);
        m |= bits << (c * 4);
    }
    if ((n >> 6) == w) m |= 1ull << (n & 63);
    adjm[id] = m;
}

// ---------------------------------------------------------------------------
// bf16 MFMA GEMM: C[M][Ncols] = A[M][K] @ BT[Ncols][K]^T + bias
// 128x128 block tile, BK=32, 256 threads, global_load_lds width-16 staging
template<bool OUT_BF16>
__global__ __launch_bounds__(256)
void gemm_mfma(const unsigned short* __restrict__ A,
               const unsigned short* __restrict__ BT,
               const float* __restrict__ bias,
               void* __restrict__ C,
               int M, int Ncols, int K) {
    const int tid  = threadIdx.x;
    const int wave = tid >> 6;
    const int lane = tid & 63;
    const int wm = (wave >> 1) * 64;
    const int wn = (wave & 1) * 64;
    const int l16 = lane & 15;
    const int lq  = lane >> 4;

    const int rowBase = blockIdx.y * 128;
    const int colBase = blockIdx.x * 128;

    __shared__ __align__(16) unsigned short As[128][32];
    __shared__ __align__(16) unsigned short Bs[128][32];

    f32x4_t acc[4][4];
#pragma unroll
    for (int i = 0; i < 4; i++)
#pragma unroll
        for (int j = 0; j < 4; j++) {
            f32x4_t z = {0.0f, 0.0f, 0.0f, 0.0f};
            acc[i][j] = z;
        }

    for (int k0 = 0; k0 < K; k0 += 32) {
        __syncthreads();
#pragma unroll
        for (int cc = 0; cc < 2; cc++) {
            int c = tid + cc * 256;           // chunk id in [0,512)
            int r = c >> 2, qq = c & 3;
            // LDS offset = c*16B, contiguous in lane order -> uniform base + lane*16
            async16(&A[(long)(rowBase + r) * K + k0 + qq * 8],
                    (unsigned short*)As + (size_t)(cc * 256 + wave * 64) * 8);
            async16(&BT[(long)(colBase + r) * K + k0 + qq * 8],
                    (unsigned short*)Bs + (size_t)(cc * 256 + wave * 64) * 8);
        }
        __syncthreads();

        bf16x8_t af[4], bfr[4];
#pragma unroll
        for (int i = 0; i < 4; i++)
            af[i] = *(bf16x8_t*)&As[wm + i * 16 + l16][lq * 8];
#pragma unroll
        for (int j = 0; j < 4; j++)
            bfr[j] = *(bf16x8_t*)&Bs[wn + j * 16 + l16][lq * 8];
#pragma unroll
        for (int i = 0; i < 4; i++)
#pragma unroll
            for (int j = 0; j < 4; j++)
                acc[i][j] = __builtin_amdgcn_mfma_f32_16x16x32_bf16(
                    af[i], bfr[j], acc[i][j], 0, 0, 0);
    }

#pragma unroll
    for (int i = 0; i < 4; i++) {
#pragma unroll
        for (int j = 0; j < 4; j++) {
            int col = colBase + wn + j * 16 + l16;
            float bv = bias[col];
#pragma unroll
            for (int r = 0; r < 4; r++) {
                int row = rowBase + wm + i * 16 + lq * 4 + r;
                float v = acc[i][j][r] + bv;
                if (OUT_BF16)
                    ((unsigned short*)C)[(long)row * Ncols + col] = f2bf(v);
                else
                    ((float*)C)[(long)row * Ncols + col] = v;
            }
        }
    }
}

// ---------------------------------------------------------------------------
// MFMA flash attention. One block per (b,h); 8 waves, wave w owns Q rows
// [w*64, w*64+64). Computes S^T tiles = K @ Q^T (so K A-frags come straight
// from LDS rows and Q frags double as B-operand), exp+mask in C-layout,
// cross-lane shuffle re-shapes P into A-operand layout (no LDS round-trip),
// PV via MFMA with V staged transposed (Vt) for contiguous B-frags.
// XOR chunk swizzle on Ks/Vt -> balanced b128 bank groups.
__global__ __launch_bounds__(512, 2)
void attn_mfma(const unsigned short* __restrict__ qkv,       // [32768][3072] bf16
               const unsigned long long* __restrict__ adjm,  // [512][8]
               unsigned short* __restrict__ y)               // [32768][1024] bf16
{
    const int h = blockIdx.x;
    const int b = blockIdx.y;
    const int tid  = threadIdx.x;
    const int lane = tid & 63;
    const int w    = tid >> 6;
    const int l16  = lane & 15;
    const int q    = lane >> 4;

    __shared__ __align__(16) unsigned short Ks[512][64];   // 64 KiB
    __shared__ __align__(16) unsigned short Vt[64][512];   // 64 KiB (V^T)

    const long rowB = (long)b * Nz;
    const unsigned short* base = qkv + rowB * NQKV;

    // ---- stage K: chunk cc of row n stored at chunk cc^(n&7)
    for (int idx = tid; idx < 4096; idx += 512) {
        int n = idx >> 3, cc = idx & 7;
        *(bf16x8_t*)&Ks[n][(cc ^ (n & 7)) * 8] =
            *(const bf16x8_t*)&base[(long)n * NQKV + Ez + h * DHz + cc * 8];
    }
    // ---- stage V transposed: Vt[d][n], chunk (n>>3) stored at (n>>3)^(d&7)
    {
        int tp = tid & 255, dh = tid >> 8;   // row-pair id, d-half
        int n0 = tp * 2;
        bf16x8_t va[4], vb[4];
#pragma unroll
        for (int c = 0; c < 4; c++) {
            va[c] = *(const bf16x8_t*)&base[(long)n0 * NQKV + 2 * Ez + h * DHz + dh * 32 + c * 8];
            vb[c] = *(const bf16x8_t*)&base[(long)(n0 + 1) * NQKV + 2 * Ez + h * DHz + dh * 32 + c * 8];
        }
        unsigned short* vt = &Vt[0][0];
#pragma unroll
        for (int dd = 0; dd < 32; dd++) {
            int d = dh * 32 + dd;
            unsigned lo = (unsigned)(unsigned short)va[dd >> 3][dd & 7];
            unsigned hi = (unsigned)(unsigned short)vb[dd >> 3][dd & 7];
            int cp = (n0 >> 3) ^ (d & 7);
            *(unsigned*)&vt[d * 512 + cp * 8 + (n0 & 7)] = lo | (hi << 16);
        }
    }
    // ---- Q A-frags in registers: qf[mt][kc] holds Q[m=w*64+mt*16+l16][kc*32+q*8+jj]
    FragU qf[4][2];
#pragma unroll
    for (int mt = 0; mt < 4; mt++)
#pragma unroll
        for (int kc = 0; kc < 2; kc++)
            qf[mt][kc].h = *(const bf16x8_t*)&base[(long)(w * 64 + mt * 16 + l16) * NQKV
                                                   + h * DHz + kc * 32 + q * 8];
    __syncthreads();   // single barrier: Ks/Vt visible; waves independent after

    f32x4_t oacc[4][4];
#pragma unroll
    for (int mt = 0; mt < 4; mt++)
#pragma unroll
        for (int dt = 0; dt < 4; dt++) {
            f32x4_t z = {0.0f, 0.0f, 0.0f, 0.0f};
            oacc[mt][dt] = z;
        }
    float rsum[4] = {0.0f, 0.0f, 0.0f, 0.0f};
    unsigned long long wm[4];

    for (int ct = 0; ct < 16; ct++) {
        const int j0 = ct * 32;
        // adjm word covers 64 cols = 2 ctiles
        if ((ct & 1) == 0) {
#pragma unroll
            for (int mt = 0; mt < 4; mt++)
                wm[mt] = adjm[(size_t)(w * 64 + mt * 16 + l16) * 8 + (ct >> 1)];
        }
        // K A-frags: rows j0+jt*16+l16, feature chunk kc*4+q (swizzled)
        bf16x8_t kf[2][2];
#pragma unroll
        for (int jt = 0; jt < 2; jt++)
#pragma unroll
            for (int kc = 0; kc < 2; kc++)
                kf[jt][kc] = *(const bf16x8_t*)
                    &Ks[j0 + jt * 16 + l16][((kc * 4 + q) ^ (l16 & 7)) * 8];

        // T = K @ Q^T : lane holds S[m=mt*16+l16][j = j0+jt*16+q*4+r]
        f32x4_t tacc[2][4];
#pragma unroll
        for (int jt = 0; jt < 2; jt++)
#pragma unroll
            for (int mt = 0; mt < 4; mt++) {
                f32x4_t z = {0.0f, 0.0f, 0.0f, 0.0f};
                z = __builtin_amdgcn_mfma_f32_16x16x32_bf16(kf[jt][0], qf[mt][0].h, z, 0, 0, 0);
                tacc[jt][mt] = __builtin_amdgcn_mfma_f32_16x16x32_bf16(kf[jt][1], qf[mt][1].h, z, 0, 0, 0);
            }

        // mask + exp + bf16-pack (pairs of r)
        unsigned pk[2][4][2];
#pragma unroll
        for (int jt = 0; jt < 2; jt++)
#pragma unroll
            for (int mt = 0; mt < 4; mt++) {
                float e[4];
#pragma unroll
                for (int r = 0; r < 4; r++) {
                    int jrel = (ct & 1) * 32 + jt * 16 + q * 4 + r;
                    bool bit = (wm[mt] >> jrel) & 1ull;
                    float ev = bit ? __expf(tacc[jt][mt][r] * 0.125f) : 0.0f;
                    e[r] = ev;
                    rsum[mt] += ev;
                }
                pk[jt][mt][0] = packbf(e[0], e[1]);
                pk[jt][mt][1] = packbf(e[2], e[3]);
            }

        // V B-frags from Vt rows (contiguous 16B, swizzled chunk)
        bf16x8_t vf[4];
#pragma unroll
        for (int dt = 0; dt < 4; dt++) {
            int d = dt * 16 + l16;
            int cp = (ct * 4 + q) ^ (l16 & 7);
            vf[dt] = *(const bf16x8_t*)&(&Vt[0][0])[d * 512 + cp * 8];
        }

        // P A-frag per mt via cross-quad shuffles, then PV MFMA
#pragma unroll
        for (int mt = 0; mt < 4; mt++) {
            FragU pf;
#pragma unroll
            for (int p = 0; p < 4; p++) {
                int srcl = ((lane & 16) << 1) | ((p & 2) << 3) | l16;
                unsigned a0 = (unsigned)__shfl((int)pk[0][mt][p & 1], srcl);
                unsigned a1 = (unsigned)__shfl((int)pk[1][mt][p & 1], srcl);
                pf.u[p] = (lane & 32) ? a1 : a0;
            }
#pragma unroll
            for (int dt = 0; dt < 4; dt++)
                oacc[mt][dt] = __builtin_amdgcn_mfma_f32_16x16x32_bf16(
                    pf.h, vf[dt], oacc[mt][dt], 0, 0, 0);
        }
    }

    // ---- epilogue: reduce rsum across quads, rescale, store
#pragma unroll
    for (int mt = 0; mt < 4; mt++) {
        float s = rsum[mt];
        s += __shfl_xor(s, 16);
        s += __shfl_xor(s, 32);   // all lanes: total for row mt*16+l16
#pragma unroll
        for (int r = 0; r < 4; r++) {
            float rs = __shfl(s, (lane & 48) | (q * 4) | r);  // row q*4+r total
            float inv = 1.0f / rs;
            int row = w * 64 + mt * 16 + q * 4 + r;
#pragma unroll
            for (int dt = 0; dt < 4; dt++)
                y[(rowB + row) * Ez + h * DHz + dt * 16 + l16] =
                    f2bf(oacc[mt][dt][r] * inv);
        }
    }
}

// ---------------------------------------------------------------------------
extern "C" void kernel_launch(void* const* d_in, const int* in_sizes, int n_in,
                              void* d_out, int out_size, void* d_ws, size_t ws_size,
                              hipStream_t stream) {
    const float* x     = (const float*)d_in[0];
    const float* Wqkv  = (const float*)d_in[1];
    const float* bqkv  = (const float*)d_in[2];
    const float* Wproj = (const float*)d_in[3];
    const float* bproj = (const float*)d_in[4];
    const int*   adj   = (const int*)d_in[5];
    float* out = (float*)d_out;

    char* ws = (char*)d_ws;
    unsigned short* xb     = (unsigned short*)(ws);                 // 67 MB (also yb)
    unsigned short* qkv    = (unsigned short*)(ws + 67108864);      // 201 MB
    unsigned short* WqkvT  = (unsigned short*)(ws + 268435456);     // 6 MB
    unsigned short* WprojT = (unsigned short*)(ws + 274726912);     // 2 MB
    unsigned long long* adjm = (unsigned long long*)(ws + 276824064); // 32 KB
    unsigned short* yb = xb;  // reuse: xb consumed by gemm1 before attn writes yb

    // 1. casts / transposes / adjacency bitmask
    cvt_f32_bf16<<<8192, 256, 0, stream>>>(x, xb, (Bz * Nz * Ez) / 4);
    cvt_transpose<<<dim3(NQKV / 256, Ez), 256, 0, stream>>>(Wqkv, WqkvT, Ez, NQKV);
    cvt_transpose<<<dim3(Ez / 256, Ez), 256, 0, stream>>>(Wproj, WprojT, Ez, Ez);
    build_adjm<<<16, 256, 0, stream>>>(adj, adjm);

    // 2. QKV projection: qkv = xb @ Wqkv + bqkv (bf16 out)
    gemm_mfma<true><<<dim3(NQKV / 128, MROWS / 128), 256, 0, stream>>>(
        xb, WqkvT, bqkv, qkv, MROWS, NQKV, Ez);

    // 3. MFMA flash attention
    attn_mfma<<<dim3(Hz, Bz), 512, 0, stream>>>(qkv, adjm, yb);

    // 4. output projection: out = yb @ Wproj + bproj (fp32 out)
    gemm_mfma<false><<<dim3(Ez / 128, MROWS / 128), 256, 0, stream>>>(
        yb, WprojT, bproj, out, MROWS, Ez, Ez);
}

// Round 3
// 801.405 us; speedup vs baseline: 3.9860x; 1.0019x over previous
//
#include <hip/hip_runtime.h>
#include <hip/hip_bf16.h>

// Problem constants
#define Bz 64
#define Nz 512
#define Ez 1024
#define Hz 16
#define DHz 64

static constexpr int MROWS = Bz * Nz;   // 32768
static constexpr int NQKV  = 3 * Ez;    // 3072

typedef __attribute__((ext_vector_type(8))) short bf16x8_t;  // 8 bf16 = 4 VGPRs
typedef __attribute__((ext_vector_type(4))) float f32x4_t;
typedef __attribute__((ext_vector_type(4))) unsigned u32x4_t;

union FragU { bf16x8_t h; u32x4_t u; };

__device__ __forceinline__ unsigned short f2bf(float f) {
    union { float f; unsigned u; } v; v.f = f;
    unsigned r = v.u + 0x7FFFu + ((v.u >> 16) & 1u);   // round-to-nearest-even
    return (unsigned short)(r >> 16);
}
__device__ __forceinline__ float bf2f(unsigned short h) {
    union { unsigned u; float f; } v; v.u = ((unsigned)h) << 16;
    return v.f;
}
// pack two non-negative floats to bf16 pair (lo | hi<<16), round-half-up
__device__ __forceinline__ unsigned packbf(float a, float b) {
    union { float f; unsigned u; } x, y; x.f = a; y.f = b;
    return ((x.u + 0x8000u) >> 16) | ((y.u + 0x8000u) & 0xFFFF0000u);
}

// async global->LDS, 16B per lane. LDS dest = wave-uniform base + lane*16.
__device__ __forceinline__ void async16(const unsigned short* g, unsigned short* l) {
    __builtin_amdgcn_global_load_lds(
        (const __attribute__((address_space(1))) void*)g,
        (__attribute__((address_space(3))) void*)l, 16, 0, 0);
}

// ---------------------------------------------------------------------------
// Convert fp32 -> bf16 (packed, vectorized)
__global__ void cvt_f32_bf16(const float* __restrict__ in,
                             unsigned short* __restrict__ out, int n4) {
    int id = blockIdx.x * blockDim.x + threadIdx.x;
    int stride = gridDim.x * blockDim.x;
    for (int i = id; i < n4; i += stride) {
        float4 f = ((const float4*)in)[i];
        ushort4 o;
        o.x = f2bf(f.x); o.y = f2bf(f.y); o.z = f2bf(f.z); o.w = f2bf(f.w);
        ((ushort4*)out)[i] = o;
    }
}

// Convert + transpose: in [K][Ncols] fp32 -> out [Ncols][K] bf16.
// Thread owns out row n, k-chunk of 8: reads 8 coalesced fp32 rows, writes
// one 16-B bf16x8 store (vs the old 2-B scattered stores).
__global__ __launch_bounds__(256)
void cvt_transpose(const float* __restrict__ in,
                   unsigned short* __restrict__ out,
                   int K, int Ncols) {
    int n  = blockIdx.x * 256 + threadIdx.x;
    int k0 = blockIdx.y * 8;
    bf16x8_t o;
#pragma unroll
    for (int j = 0; j < 8; j++)
        o[j] = (short)f2bf(in[(long)(k0 + j) * Ncols + n]);
    *(bf16x8_t*)&out[(long)n * K + k0] = o;
}

// adj[512][512] int -> bitmask adjm[512][8] u64, self-loops baked in
__global__ void build_adjm(const int* __restrict__ adj,
                           unsigned long long* __restrict__ adjm) {
    int id = blockIdx.x * blockDim.x + threadIdx.x;   // 0..4095
    int n = id >> 3, w = id & 7;
    const int4* r4 = (const int4*)(adj + (long)n * Nz + w * 64);
    unsigned long long m = 0;
#pragma unroll
    for (int c = 0; c < 16; c++) {
        int4 v = r4[c];
        unsigned long long bits =
            (unsigned long long)(v.x != 0) | ((unsigned long long)(v.y != 0) << 1) |
            ((unsigned long long)(v.z != 0) << 2) | ((unsigned long long)(v.w != 0) << 3);
        m |= bits << (c * 4);
    }
    if ((n >> 6) == w) m |= 1ull << (n & 63);
    adjm[id] = m;
}

// ---------------------------------------------------------------------------
// bf16 MFMA GEMM: C[M][Ncols] = A[M][K] @ BT[Ncols][K]^T + bias
// 128x128 block tile, BK=32, 256 threads, global_load_lds width-16 staging.
// LDS XOR swizzle: physical 16-B chunk p of row r holds logical chunk
// p ^ ((r>>1)&3). Staging permutes lanes' global chunk (within the same 64-B
// row segment -> still coalesced); fragment b128 reads then hit all 8 bank
// quads per lane-octet (kills the 2.5e7 bank conflicts of the linear layout).
template<bool OUT_BF16>
__global__ __launch_bounds__(256)
void gemm_mfma(const unsigned short* __restrict__ A,
               const unsigned short* __restrict__ BT,
               const float* __restrict__ bias,
               void* __restrict__ C,
               int M, int Ncols, int K) {
    const int tid  = threadIdx.x;
    const int wave = tid >> 6;
    const int lane = tid & 63;
    const int wm = (wave >> 1) * 64;
    const int wn = (wave & 1) * 64;
    const int l16 = lane & 15;
    const int lq  = lane >> 4;

    const int rowBase = blockIdx.y * 128;
    const int colBase = blockIdx.x * 128;

    __shared__ __align__(16) unsigned short As[128][32];
    __shared__ __align__(16) unsigned short Bs[128][32];

    f32x4_t acc[4][4];
#pragma unroll
    for (int i = 0; i < 4; i++)
#pragma unroll
        for (int j = 0; j < 4; j++) {
            f32x4_t z = {0.0f, 0.0f, 0.0f, 0.0f};
            acc[i][j] = z;
        }

    // per-thread staging source (slot s = tid + cc*256): row r=s>>2, physical
    // chunk p=s&3 receives logical chunk qq = p ^ ((r>>1)&3)
    int srow[2], sqq[2];
#pragma unroll
    for (int cc = 0; cc < 2; cc++) {
        int s = tid + cc * 256;
        int r = s >> 2, p = s & 3;
        srow[cc] = r;
        sqq[cc]  = p ^ ((r >> 1) & 3);
    }
    const int fsw = ((l16 >> 1) & 3);  // fragment-read swizzle term

    for (int k0 = 0; k0 < K; k0 += 32) {
        __syncthreads();
#pragma unroll
        for (int cc = 0; cc < 2; cc++) {
            async16(&A[(long)(rowBase + srow[cc]) * K + k0 + sqq[cc] * 8],
                    (unsigned short*)As + (size_t)(cc * 256 + wave * 64) * 8);
            async16(&BT[(long)(colBase + srow[cc]) * K + k0 + sqq[cc] * 8],
                    (unsigned short*)Bs + (size_t)(cc * 256 + wave * 64) * 8);
        }
        __syncthreads();

        bf16x8_t af[4], bfr[4];
#pragma unroll
        for (int i = 0; i < 4; i++)
            af[i] = *(bf16x8_t*)&As[wm + i * 16 + l16][(lq ^ fsw) * 8];
#pragma unroll
        for (int j = 0; j < 4; j++)
            bfr[j] = *(bf16x8_t*)&Bs[wn + j * 16 + l16][(lq ^ fsw) * 8];
#pragma unroll
        for (int i = 0; i < 4; i++)
#pragma unroll
            for (int j = 0; j < 4; j++)
                acc[i][j] = __builtin_amdgcn_mfma_f32_16x16x32_bf16(
                    af[i], bfr[j], acc[i][j], 0, 0, 0);
    }

#pragma unroll
    for (int i = 0; i < 4; i++) {
#pragma unroll
        for (int j = 0; j < 4; j++) {
            int col = colBase + wn + j * 16 + l16;
            float bv = bias[col];
#pragma unroll
            for (int r = 0; r < 4; r++) {
                int row = rowBase + wm + i * 16 + lq * 4 + r;
                float v = acc[i][j][r] + bv;
                if (OUT_BF16)
                    ((unsigned short*)C)[(long)row * Ncols + col] = f2bf(v);
                else
                    ((float*)C)[(long)row * Ncols + col] = v;
            }
        }
    }
}

// ---------------------------------------------------------------------------
// MFMA flash attention. One block per (b,h); 8 waves, wave w owns Q rows
// [w*64, w*64+64). Computes S^T tiles = K @ Q^T, exp+mask in C-layout,
// cross-lane shuffle re-shapes P into A-operand layout (no LDS round-trip),
// PV via MFMA with V staged transposed (Vt) for contiguous B-frags.
__global__ __launch_bounds__(512, 2)
void attn_mfma(const unsigned short* __restrict__ qkv,       // [32768][3072] bf16
               const unsigned long long* __restrict__ adjm,  // [512][8]
               unsigned short* __restrict__ y)               // [32768][1024] bf16
{
    const int h = blockIdx.x;
    const int b = blockIdx.y;
    const int tid  = threadIdx.x;
    const int lane = tid & 63;
    const int w    = tid >> 6;
    const int l16  = lane & 15;
    const int q    = lane >> 4;

    __shared__ __align__(16) unsigned short Ks[512][64];   // 64 KiB
    __shared__ __align__(16) unsigned short Vt[64][512];   // 64 KiB (V^T)

    const long rowB = (long)b * Nz;
    const unsigned short* base = qkv + rowB * NQKV;

    // ---- stage K: chunk cc of row n stored at chunk cc^(n&7)
    for (int idx = tid; idx < 4096; idx += 512) {
        int n = idx >> 3, cc = idx & 7;
        *(bf16x8_t*)&Ks[n][(cc ^ (n & 7)) * 8] =
            *(const bf16x8_t*)&base[(long)n * NQKV + Ez + h * DHz + cc * 8];
    }
    // ---- stage V transposed: Vt[d][n], chunk (n>>3) stored at (n>>3)^(d&7)
    {
        int tp = tid & 255, dh = tid >> 8;   // row-pair id, d-half
        int n0 = tp * 2;
        bf16x8_t va[4], vb[4];
#pragma unroll
        for (int c = 0; c < 4; c++) {
            va[c] = *(const bf16x8_t*)&base[(long)n0 * NQKV + 2 * Ez + h * DHz + dh * 32 + c * 8];
            vb[c] = *(const bf16x8_t*)&base[(long)(n0 + 1) * NQKV + 2 * Ez + h * DHz + dh * 32 + c * 8];
        }
        unsigned short* vt = &Vt[0][0];
#pragma unroll
        for (int dd = 0; dd < 32; dd++) {
            int d = dh * 32 + dd;
            unsigned lo = (unsigned)(unsigned short)va[dd >> 3][dd & 7];
            unsigned hi = (unsigned)(unsigned short)vb[dd >> 3][dd & 7];
            int cp = (n0 >> 3) ^ (d & 7);
            *(unsigned*)&vt[d * 512 + cp * 8 + (n0 & 7)] = lo | (hi << 16);
        }
    }
    // ---- Q A-frags in registers
    FragU qf[4][2];
#pragma unroll
    for (int mt = 0; mt < 4; mt++)
#pragma unroll
        for (int kc = 0; kc < 2; kc++)
            qf[mt][kc].h = *(const bf16x8_t*)&base[(long)(w * 64 + mt * 16 + l16) * NQKV
                                                   + h * DHz + kc * 32 + q * 8];
    __syncthreads();   // single barrier: Ks/Vt visible; waves independent after

    f32x4_t oacc[4][4];
#pragma unroll
    for (int mt = 0; mt < 4; mt++)
#pragma unroll
        for (int dt = 0; dt < 4; dt++) {
            f32x4_t z = {0.0f, 0.0f, 0.0f, 0.0f};
            oacc[mt][dt] = z;
        }
    float rsum[4] = {0.0f, 0.0f, 0.0f, 0.0f};
    unsigned long long wm[4];

    for (int ct = 0; ct < 16; ct++) {
        const int j0 = ct * 32;
        if ((ct & 1) == 0) {
#pragma unroll
            for (int mt = 0; mt < 4; mt++)
                wm[mt] = adjm[(size_t)(w * 64 + mt * 16 + l16) * 8 + (ct >> 1)];
        }
        bf16x8_t kf[2][2];
#pragma unroll
        for (int jt = 0; jt < 2; jt++)
#pragma unroll
            for (int kc = 0; kc < 2; kc++)
                kf[jt][kc] = *(const bf16x8_t*)
                    &Ks[j0 + jt * 16 + l16][((kc * 4 + q) ^ (l16 & 7)) * 8];

        f32x4_t tacc[2][4];
#pragma unroll
        for (int jt = 0; jt < 2; jt++)
#pragma unroll
            for (int mt = 0; mt < 4; mt++) {
                f32x4_t z = {0.0f, 0.0f, 0.0f, 0.0f};
                z = __builtin_amdgcn_mfma_f32_16x16x32_bf16(kf[jt][0], qf[mt][0].h, z, 0, 0, 0);
                tacc[jt][mt] = __builtin_amdgcn_mfma_f32_16x16x32_bf16(kf[jt][1], qf[mt][1].h, z, 0, 0, 0);
            }

        unsigned pk[2][4][2];
#pragma unroll
        for (int jt = 0; jt < 2; jt++)
#pragma unroll
            for (int mt = 0; mt < 4; mt++) {
                float e[4];
#pragma unroll
                for (int r = 0; r < 4; r++) {
                    int jrel = (ct & 1) * 32 + jt * 16 + q * 4 + r;
                    bool bit = (wm[mt] >> jrel) & 1ull;
                    float ev = bit ? __expf(tacc[jt][mt][r] * 0.125f) : 0.0f;
                    e[r] = ev;
                    rsum[mt] += ev;
                }
                pk[jt][mt][0] = packbf(e[0], e[1]);
                pk[jt][mt][1] = packbf(e[2], e[3]);
            }

        bf16x8_t vf[4];
#pragma unroll
        for (int dt = 0; dt < 4; dt++) {
            int d = dt * 16 + l16;
            int cp = (ct * 4 + q) ^ (l16 & 7);
            vf[dt] = *(const bf16x8_t*)&(&Vt[0][0])[d * 512 + cp * 8];
        }

#pragma unroll
        for (int mt = 0; mt < 4; mt++) {
            FragU pf;
#pragma unroll
            for (int p = 0; p < 4; p++) {
                int srcl = ((lane & 16) << 1) | ((p & 2) << 3) | l16;
                unsigned a0 = (unsigned)__shfl((int)pk[0][mt][p & 1], srcl);
                unsigned a1 = (unsigned)__shfl((int)pk[1][mt][p & 1], srcl);
                pf.u[p] = (lane & 32) ? a1 : a0;
            }
#pragma unroll
            for (int dt = 0; dt < 4; dt++)
                oacc[mt][dt] = __builtin_amdgcn_mfma_f32_16x16x32_bf16(
                    pf.h, vf[dt], oacc[mt][dt], 0, 0, 0);
        }
    }

    // ---- epilogue: reduce rsum across quads, rescale, store
#pragma unroll
    for (int mt = 0; mt < 4; mt++) {
        float s = rsum[mt];
        s += __shfl_xor(s, 16);
        s += __shfl_xor(s, 32);
#pragma unroll
        for (int r = 0; r < 4; r++) {
            float rs = __shfl(s, (lane & 48) | (q * 4) | r);
            float inv = 1.0f / rs;
            int row = w * 64 + mt * 16 + q * 4 + r;
#pragma unroll
            for (int dt = 0; dt < 4; dt++)
                y[(rowB + row) * Ez + h * DHz + dt * 16 + l16] =
                    f2bf(oacc[mt][dt][r] * inv);
        }
    }
}

// ---------------------------------------------------------------------------
extern "C" void kernel_launch(void* const* d_in, const int* in_sizes, int n_in,
                              void* d_out, int out_size, void* d_ws, size_t ws_size,
                              hipStream_t stream) {
    const float* x     = (const float*)d_in[0];
    const float* Wqkv  = (const float*)d_in[1];
    const float* bqkv  = (const float*)d_in[2];
    const float* Wproj = (const float*)d_in[3];
    const float* bproj = (const float*)d_in[4];
    const int*   adj   = (const int*)d_in[5];
    float* out = (float*)d_out;

    char* ws = (char*)d_ws;
    unsigned short* xb     = (unsigned short*)(ws);                 // 67 MB (also yb)
    unsigned short* qkv    = (unsigned short*)(ws + 67108864);      // 201 MB
    unsigned short* WqkvT  = (unsigned short*)(ws + 268435456);     // 6 MB
    unsigned short* WprojT = (unsigned short*)(ws + 274726912);     // 2 MB
    unsigned long long* adjm = (unsigned long long*)(ws + 276824064); // 32 KB
    unsigned short* yb = xb;  // reuse: xb consumed by gemm1 before attn writes yb

    // 1. casts / transposes / adjacency bitmask
    cvt_f32_bf16<<<8192, 256, 0, stream>>>(x, xb, (Bz * Nz * Ez) / 4);
    cvt_transpose<<<dim3(NQKV / 256, Ez / 8), 256, 0, stream>>>(Wqkv, WqkvT, Ez, NQKV);
    cvt_transpose<<<dim3(Ez / 256, Ez / 8), 256, 0, stream>>>(Wproj, WprojT, Ez, Ez);
    build_adjm<<<16, 256, 0, stream>>>(adj, adjm);

    // 2. QKV projection: qkv = xb @ Wqkv + bqkv (bf16 out)
    gemm_mfma<true><<<dim3(NQKV / 128, MROWS / 128), 256, 0, stream>>>(
        xb, WqkvT, bqkv, qkv, MROWS, NQKV, Ez);

    // 3. MFMA flash attention
    attn_mfma<<<dim3(Hz, Bz), 512, 0, stream>>>(qkv, adjm, yb);

    // 4. output projection: out = yb @ Wproj + bproj (fp32 out)
    gemm_mfma<false><<<dim3(Ez / 128, MROWS / 128), 256, 0, stream>>>(
        yb, WprojT, bproj, out, MROWS, Ez, Ez);
}

// Round 4
// 756.207 us; speedup vs baseline: 4.2242x; 1.0598x over previous
//
#include <hip/hip_runtime.h>
#include <hip/hip_bf16.h>

// Problem constants
#define Bz 64
#define Nz 512
#define Ez 1024
#define Hz 16
#define DHz 64

static constexpr int MROWS = Bz * Nz;   // 32768
static constexpr int NQKV  = 3 * Ez;    // 3072

typedef __attribute__((ext_vector_type(8))) short bf16x8_t;   // 8 bf16 = 4 VGPRs
typedef __attribute__((ext_vector_type(4))) float f32x4_t;
typedef __attribute__((ext_vector_type(16))) float f32x16_t;
typedef __attribute__((ext_vector_type(4))) unsigned u32x4_t;

union FragU { bf16x8_t h; u32x4_t u; };

__device__ __forceinline__ unsigned short f2bf(float f) {
    union { float f; unsigned u; } v; v.f = f;
    unsigned r = v.u + 0x7FFFu + ((v.u >> 16) & 1u);   // round-to-nearest-even
    return (unsigned short)(r >> 16);
}
__device__ __forceinline__ float bf2f(unsigned short h) {
    union { unsigned u; float f; } v; v.u = ((unsigned)h) << 16;
    return v.f;
}
// pack two non-negative floats to bf16 pair (lo | hi<<16), round-half-up
__device__ __forceinline__ unsigned packbf(float a, float b) {
    union { float f; unsigned u; } x, y; x.f = a; y.f = b;
    return ((x.u + 0x8000u) >> 16) | ((y.u + 0x8000u) & 0xFFFF0000u);
}

// async global->LDS, 16B per lane. LDS dest = wave-uniform base + lane*16.
__device__ __forceinline__ void async16(const unsigned short* g, unsigned short* l) {
    __builtin_amdgcn_global_load_lds(
        (const __attribute__((address_space(1))) void*)g,
        (__attribute__((address_space(3))) void*)l, 16, 0, 0);
}

// ---------------------------------------------------------------------------
// Convert fp32 -> bf16 (packed, vectorized)
__global__ void cvt_f32_bf16(const float* __restrict__ in,
                             unsigned short* __restrict__ out, int n4) {
    int id = blockIdx.x * blockDim.x + threadIdx.x;
    int stride = gridDim.x * blockDim.x;
    for (int i = id; i < n4; i += stride) {
        float4 f = ((const float4*)in)[i];
        ushort4 o;
        o.x = f2bf(f.x); o.y = f2bf(f.y); o.z = f2bf(f.z); o.w = f2bf(f.w);
        ((ushort4*)out)[i] = o;
    }
}

// Convert + transpose: in [K][Ncols] fp32 -> out [Ncols][K] bf16.
__global__ __launch_bounds__(256)
void cvt_transpose(const float* __restrict__ in,
                   unsigned short* __restrict__ out,
                   int K, int Ncols) {
    int n  = blockIdx.x * 256 + threadIdx.x;
    int k0 = blockIdx.y * 8;
    bf16x8_t o;
#pragma unroll
    for (int j = 0; j < 8; j++)
        o[j] = (short)f2bf(in[(long)(k0 + j) * Ncols + n]);
    *(bf16x8_t*)&out[(long)n * K + k0] = o;
}

// adj[512][512] int -> bitmask adjm[512][8] u64, self-loops baked in
__global__ void build_adjm(const int* __restrict__ adj,
                           unsigned long long* __restrict__ adjm) {
    int id = blockIdx.x * blockDim.x + threadIdx.x;   // 0..4095
    int n = id >> 3, w = id & 7;
    const int4* r4 = (const int4*)(adj + (long)n * Nz + w * 64);
    unsigned long long m = 0;
#pragma unroll
    for (int c = 0; c < 16; c++) {
        int4 v = r4[c];
        unsigned long long bits =
            (unsigned long long)(v.x != 0) | ((unsigned long long)(v.y != 0) << 1) |
            ((unsigned long long)(v.z != 0) << 2) | ((unsigned long long)(v.w != 0) << 3);
        m |= bits << (c * 4);
    }
    if ((n >> 6) == w) m |= 1ull << (n & 63);
    adjm[id] = m;
}

// ---------------------------------------------------------------------------
// bf16 MFMA GEMM v4: C[M][Ncols] = A[M][K] @ BT[Ncols][K]^T + bias
// 128x128 block tile, BK=64 (16 barriers for K=1024), 32x32x16 MFMA,
// global_load_lds width-16 staging, XOR-8 chunk swizzle (p = c ^ (row&7)).
// Frag b128 reads: per 16-lane phase, 8 distinct 4-bank groups x 2-way = free.
template<bool OUT_BF16>
__global__ __launch_bounds__(256)
void gemm_mfma(const unsigned short* __restrict__ A,
               const unsigned short* __restrict__ BT,
               const float* __restrict__ bias,
               void* __restrict__ C,
               int M, int Ncols, int K) {
    const int tid  = threadIdx.x;
    const int wave = tid >> 6;
    const int lane = tid & 63;
    const int wm = (wave >> 1) * 64;
    const int wn = (wave & 1) * 64;
    const int m32 = lane & 31;     // row within 32-tile
    const int kh  = lane >> 5;     // k-half selector

    const int rowBase = blockIdx.y * 128;
    const int colBase = blockIdx.x * 128;

    __shared__ __align__(16) unsigned short As[128][64];   // 16 KiB
    __shared__ __align__(16) unsigned short Bs[128][64];   // 16 KiB

    f32x16_t acc[2][2];
#pragma unroll
    for (int i = 0; i < 2; i++)
#pragma unroll
        for (int j = 0; j < 2; j++)
#pragma unroll
            for (int r = 0; r < 16; r++)
                acc[i][j][r] = 0.0f;

    // staging: slot s = tid + cc*256 (s in [0,1024)); row = s>>3, physical
    // chunk p = s&7 holds logical chunk c = p ^ (row&7). Global addresses of
    // 8 consecutive lanes permute within one 128B row segment -> coalesced.
    const unsigned short* pa[4];
    const unsigned short* pb[4];
#pragma unroll
    for (int cc = 0; cc < 4; cc++) {
        int s = tid + cc * 256;
        int r = s >> 3;
        int c = (s & 7) ^ (r & 7);
        pa[cc] = &A [(long)(rowBase + r) * K + c * 8];
        pb[cc] = &BT[(long)(colBase + r) * K + c * 8];
    }
    // fragment-read physical chunk, per kc: p = (kc*2 + kh) ^ (m32&7)
    const int fsw = m32 & 7;

    for (int k0 = 0; k0 < K; k0 += 64) {
        __syncthreads();
#pragma unroll
        for (int cc = 0; cc < 4; cc++) {
            async16(pa[cc] + k0, (unsigned short*)As + (size_t)(cc * 64 + wave * 16) * 32);
            async16(pb[cc] + k0, (unsigned short*)Bs + (size_t)(cc * 64 + wave * 16) * 32);
        }
        __syncthreads();

        bf16x8_t af[2][4], bfr[2][4];
#pragma unroll
        for (int kc = 0; kc < 4; kc++) {
            int p = (kc * 2 + kh) ^ fsw;
#pragma unroll
            for (int t = 0; t < 2; t++) {
                af[t][kc]  = *(bf16x8_t*)&As[wm + t * 32 + m32][p * 8];
                bfr[t][kc] = *(bf16x8_t*)&Bs[wn + t * 32 + m32][p * 8];
            }
        }
#pragma unroll
        for (int kc = 0; kc < 4; kc++)
#pragma unroll
            for (int i = 0; i < 2; i++)
#pragma unroll
                for (int j = 0; j < 2; j++)
                    acc[i][j] = __builtin_amdgcn_mfma_f32_32x32x16_bf16(
                        af[i][kc], bfr[j][kc], acc[i][j], 0, 0, 0);
    }

    // epilogue: C/D layout col=lane&31, row=(reg&3)+8*(reg>>2)+4*kh
#pragma unroll
    for (int j = 0; j < 2; j++) {
        int col = colBase + wn + j * 32 + m32;
        float bv = bias[col];
#pragma unroll
        for (int i = 0; i < 2; i++) {
#pragma unroll
            for (int reg = 0; reg < 16; reg++) {
                int row = rowBase + wm + i * 32 + (reg & 3) + 8 * (reg >> 2) + 4 * kh;
                float v = acc[i][j][reg] + bv;
                if (OUT_BF16)
                    ((unsigned short*)C)[(long)row * Ncols + col] = f2bf(v);
                else
                    ((float*)C)[(long)row * Ncols + col] = v;
            }
        }
    }
}

// ---------------------------------------------------------------------------
// MFMA flash attention (unchanged from round 3). One block per (b,h); 8
// waves, wave w owns Q rows [w*64, w*64+64). S^T = K @ Q^T via 16x16x32
// MFMA, exp+mask in C-layout, shuffle re-layout P -> A-operand, PV MFMA
// with V staged transposed.
__global__ __launch_bounds__(512, 2)
void attn_mfma(const unsigned short* __restrict__ qkv,       // [32768][3072] bf16
               const unsigned long long* __restrict__ adjm,  // [512][8]
               unsigned short* __restrict__ y)               // [32768][1024] bf16
{
    const int h = blockIdx.x;
    const int b = blockIdx.y;
    const int tid  = threadIdx.x;
    const int lane = tid & 63;
    const int w    = tid >> 6;
    const int l16  = lane & 15;
    const int q    = lane >> 4;

    __shared__ __align__(16) unsigned short Ks[512][64];   // 64 KiB
    __shared__ __align__(16) unsigned short Vt[64][512];   // 64 KiB (V^T)

    const long rowB = (long)b * Nz;
    const unsigned short* base = qkv + rowB * NQKV;

    for (int idx = tid; idx < 4096; idx += 512) {
        int n = idx >> 3, cc = idx & 7;
        *(bf16x8_t*)&Ks[n][(cc ^ (n & 7)) * 8] =
            *(const bf16x8_t*)&base[(long)n * NQKV + Ez + h * DHz + cc * 8];
    }
    {
        int tp = tid & 255, dh = tid >> 8;
        int n0 = tp * 2;
        bf16x8_t va[4], vb[4];
#pragma unroll
        for (int c = 0; c < 4; c++) {
            va[c] = *(const bf16x8_t*)&base[(long)n0 * NQKV + 2 * Ez + h * DHz + dh * 32 + c * 8];
            vb[c] = *(const bf16x8_t*)&base[(long)(n0 + 1) * NQKV + 2 * Ez + h * DHz + dh * 32 + c * 8];
        }
        unsigned short* vt = &Vt[0][0];
#pragma unroll
        for (int dd = 0; dd < 32; dd++) {
            int d = dh * 32 + dd;
            unsigned lo = (unsigned)(unsigned short)va[dd >> 3][dd & 7];
            unsigned hi = (unsigned)(unsigned short)vb[dd >> 3][dd & 7];
            int cp = (n0 >> 3) ^ (d & 7);
            *(unsigned*)&vt[d * 512 + cp * 8 + (n0 & 7)] = lo | (hi << 16);
        }
    }
    FragU qf[4][2];
#pragma unroll
    for (int mt = 0; mt < 4; mt++)
#pragma unroll
        for (int kc = 0; kc < 2; kc++)
            qf[mt][kc].h = *(const bf16x8_t*)&base[(long)(w * 64 + mt * 16 + l16) * NQKV
                                                   + h * DHz + kc * 32 + q * 8];
    __syncthreads();

    f32x4_t oacc[4][4];
#pragma unroll
    for (int mt = 0; mt < 4; mt++)
#pragma unroll
        for (int dt = 0; dt < 4; dt++) {
            f32x4_t z = {0.0f, 0.0f, 0.0f, 0.0f};
            oacc[mt][dt] = z;
        }
    float rsum[4] = {0.0f, 0.0f, 0.0f, 0.0f};
    unsigned long long wm[4];

    for (int ct = 0; ct < 16; ct++) {
        const int j0 = ct * 32;
        if ((ct & 1) == 0) {
#pragma unroll
            for (int mt = 0; mt < 4; mt++)
                wm[mt] = adjm[(size_t)(w * 64 + mt * 16 + l16) * 8 + (ct >> 1)];
        }
        bf16x8_t kf[2][2];
#pragma unroll
        for (int jt = 0; jt < 2; jt++)
#pragma unroll
            for (int kc = 0; kc < 2; kc++)
                kf[jt][kc] = *(const bf16x8_t*)
                    &Ks[j0 + jt * 16 + l16][((kc * 4 + q) ^ (l16 & 7)) * 8];

        f32x4_t tacc[2][4];
#pragma unroll
        for (int jt = 0; jt < 2; jt++)
#pragma unroll
            for (int mt = 0; mt < 4; mt++) {
                f32x4_t z = {0.0f, 0.0f, 0.0f, 0.0f};
                z = __builtin_amdgcn_mfma_f32_16x16x32_bf16(kf[jt][0], qf[mt][0].h, z, 0, 0, 0);
                tacc[jt][mt] = __builtin_amdgcn_mfma_f32_16x16x32_bf16(kf[jt][1], qf[mt][1].h, z, 0, 0, 0);
            }

        unsigned pk[2][4][2];
#pragma unroll
        for (int jt = 0; jt < 2; jt++)
#pragma unroll
            for (int mt = 0; mt < 4; mt++) {
                float e[4];
#pragma unroll
                for (int r = 0; r < 4; r++) {
                    int jrel = (ct & 1) * 32 + jt * 16 + q * 4 + r;
                    bool bit = (wm[mt] >> jrel) & 1ull;
                    float ev = bit ? __expf(tacc[jt][mt][r] * 0.125f) : 0.0f;
                    e[r] = ev;
                    rsum[mt] += ev;
                }
                pk[jt][mt][0] = packbf(e[0], e[1]);
                pk[jt][mt][1] = packbf(e[2], e[3]);
            }

        bf16x8_t vf[4];
#pragma unroll
        for (int dt = 0; dt < 4; dt++) {
            int d = dt * 16 + l16;
            int cp = (ct * 4 + q) ^ (l16 & 7);
            vf[dt] = *(const bf16x8_t*)&(&Vt[0][0])[d * 512 + cp * 8];
        }

#pragma unroll
        for (int mt = 0; mt < 4; mt++) {
            FragU pf;
#pragma unroll
            for (int p = 0; p < 4; p++) {
                int srcl = ((lane & 16) << 1) | ((p & 2) << 3) | l16;
                unsigned a0 = (unsigned)__shfl((int)pk[0][mt][p & 1], srcl);
                unsigned a1 = (unsigned)__shfl((int)pk[1][mt][p & 1], srcl);
                pf.u[p] = (lane & 32) ? a1 : a0;
            }
#pragma unroll
            for (int dt = 0; dt < 4; dt++)
                oacc[mt][dt] = __builtin_amdgcn_mfma_f32_16x16x32_bf16(
                    pf.h, vf[dt], oacc[mt][dt], 0, 0, 0);
        }
    }

#pragma unroll
    for (int mt = 0; mt < 4; mt++) {
        float s = rsum[mt];
        s += __shfl_xor(s, 16);
        s += __shfl_xor(s, 32);
#pragma unroll
        for (int r = 0; r < 4; r++) {
            float rs = __shfl(s, (lane & 48) | (q * 4) | r);
            float inv = 1.0f / rs;
            int row = w * 64 + mt * 16 + q * 4 + r;
#pragma unroll
            for (int dt = 0; dt < 4; dt++)
                y[(rowB + row) * Ez + h * DHz + dt * 16 + l16] =
                    f2bf(oacc[mt][dt][r] * inv);
        }
    }
}

// ---------------------------------------------------------------------------
extern "C" void kernel_launch(void* const* d_in, const int* in_sizes, int n_in,
                              void* d_out, int out_size, void* d_ws, size_t ws_size,
                              hipStream_t stream) {
    const float* x     = (const float*)d_in[0];
    const float* Wqkv  = (const float*)d_in[1];
    const float* bqkv  = (const float*)d_in[2];
    const float* Wproj = (const float*)d_in[3];
    const float* bproj = (const float*)d_in[4];
    const int*   adj   = (const int*)d_in[5];
    float* out = (float*)d_out;

    char* ws = (char*)d_ws;
    unsigned short* xb     = (unsigned short*)(ws);                 // 67 MB (also yb)
    unsigned short* qkv    = (unsigned short*)(ws + 67108864);      // 201 MB
    unsigned short* WqkvT  = (unsigned short*)(ws + 268435456);     // 6 MB
    unsigned short* WprojT = (unsigned short*)(ws + 274726912);     // 2 MB
    unsigned long long* adjm = (unsigned long long*)(ws + 276824064); // 32 KB
    unsigned short* yb = xb;  // reuse: xb consumed by gemm1 before attn writes yb

    // 1. casts / transposes / adjacency bitmask
    cvt_f32_bf16<<<8192, 256, 0, stream>>>(x, xb, (Bz * Nz * Ez) / 4);
    cvt_transpose<<<dim3(NQKV / 256, Ez / 8), 256, 0, stream>>>(Wqkv, WqkvT, Ez, NQKV);
    cvt_transpose<<<dim3(Ez / 256, Ez / 8), 256, 0, stream>>>(Wproj, WprojT, Ez, Ez);
    build_adjm<<<16, 256, 0, stream>>>(adj, adjm);

    // 2. QKV projection: qkv = xb @ Wqkv + bqkv (bf16 out)
    gemm_mfma<true><<<dim3(NQKV / 128, MROWS / 128), 256, 0, stream>>>(
        xb, WqkvT, bqkv, qkv, MROWS, NQKV, Ez);

    // 3. MFMA flash attention
    attn_mfma<<<dim3(Hz, Bz), 512, 0, stream>>>(qkv, adjm, yb);

    // 4. output projection: out = yb @ Wproj + bproj (fp32 out)
    gemm_mfma<false><<<dim3(Ez / 128, MROWS / 128), 256, 0, stream>>>(
        yb, WprojT, bproj, out, MROWS, Ez, Ez);
}